// Round 4
// baseline (1409.432 us; speedup 1.0000x reference)
//
#include <hip/hip_runtime.h>

// Sinkhorn image loss — single persistent kernel, K held in registers.
//   p = softmax(pred_logits) ; q = target + 1e-8 ; K = exp(-C/eps), eps=0.01
//   a1 = p / rowsum(K) ; alternate b = q/(K a), a = p/(K b)  (10 pairs)
//   cost_b = sum_ij a_i b_j K_ij C_ij ; out = mean_b
//
// 768 one-wave blocks (3/CU, all co-resident at 1 wave/SIMD). Each wave owns
// 6 K-rows x 8 batches: K slab = 54 float4 = 216 VGPRs, loaded+exp'd ONCE.
// All 19 matvec passes run from registers; only the 147 KB dual vectors move
// through memory per pass. Grid sync via hierarchical device-scope atomic
// barrier (16 leaves + super, release on arrive / acquire on depart — the
// compiler emits the L2 writeback/invalidate needed across XCDs).
// f32-safe: K_ii = 1 bounds every row-sum below; exp(-100)->0 under FTZ is
// exact to 4e-44.

namespace {

constexpr int N  = 2304;   // 48*48
constexpr int B  = 16;
constexpr int NB = N * B;

__device__ __forceinline__ float4 expk4(float4 c) {
    float4 k;
    k.x = __expf(c.x * -100.f);
    k.y = __expf(c.y * -100.f);
    k.z = __expf(c.z * -100.f);
    k.w = __expf(c.w * -100.f);
    return k;
}

__device__ __forceinline__ float wave_sum(float v) {
#pragma unroll
    for (int off = 32; off >= 1; off >>= 1) v += __shfl_xor(v, off);
    return v;
}

// Fold-reduce: NV values/lane -> NV/2, consuming lane bit `bit`.
// After folding bits 1,2,4,8: slot k on lane l holds the 16-lane-group sum
// of original index 16k + (l & 15)... (validated in round 3: absmax 0.0)
template <int NV>
__device__ __forceinline__ void fold(float* v, int bit) {
    const bool hi = (threadIdx.x & bit) != 0;
#pragma unroll
    for (int k = 0; k < NV / 2; ++k) {
        const float a = hi ? v[2 * k + 1] : v[2 * k];
        const float b = hi ? v[2 * k]     : v[2 * k + 1];
        v[k] = a + __shfl_xor(b, bit);
    }
}

// Grid barrier: 768 blocks, 16 leaf counters (128 B apart) + 1 super.
// Monotone phase counts (counters zeroed by memset each launch).
__device__ __forceinline__ void gridbar(int* __restrict__ bar, int phase) {
    int* super = bar + 512;
    if (threadIdx.x == 0) {
        int* leaf = bar + ((blockIdx.x & 15) << 5);
        const int old = __hip_atomic_fetch_add(leaf, 1, __ATOMIC_ACQ_REL,
                                               __HIP_MEMORY_SCOPE_AGENT);
        if (old == phase * 48 - 1)
            __hip_atomic_fetch_add(super, 1, __ATOMIC_ACQ_REL,
                                   __HIP_MEMORY_SCOPE_AGENT);
        while (__hip_atomic_load(super, __ATOMIC_ACQUIRE,
                                 __HIP_MEMORY_SCOPE_AGENT) < phase * 16)
            __builtin_amdgcn_s_sleep(1);
    }
    // wave reconverges here; lane0's acquire (s_waitcnt + cache inv) is
    // wave/CU-wide, ordering all subsequent loads.
}

// One scaling pass from register-resident K:
//   dst[b][i] = src[b][i] / sum_j K[i][j] * win[b][j]
__device__ __forceinline__ void halfpass(const float4 (&K)[6][9],
                                         const float* __restrict__ win,
                                         const float* __restrict__ src,
                                         float* __restrict__ dst,
                                         int i0, int b0, int jl, int lane) {
    float v[48];
#pragma unroll
    for (int k = 0; k < 48; ++k) v[k] = 0.f;

    float4 wb[2][8];
#pragma unroll
    for (int bb = 0; bb < 8; ++bb)
        wb[0][bb] = *(const float4*)(win + (b0 + bb) * N + jl);

#pragma unroll
    for (int it = 0; it < 9; ++it) {
        const int cur = it & 1, nxt = cur ^ 1;
        if (it < 8) {  // compile-time after unroll
            const int j0 = (it + 1) * 256 + jl;
#pragma unroll
            for (int bb = 0; bb < 8; ++bb)
                wb[nxt][bb] = *(const float4*)(win + (b0 + bb) * N + j0);
        }
#pragma unroll
        for (int r = 0; r < 6; ++r) {
            const float4 k4 = K[r][it];
#pragma unroll
            for (int bb = 0; bb < 8; ++bb) {
                const float4 w4 = wb[cur][bb];
                float& a = v[r * 8 + bb];
                a = fmaf(k4.x, w4.x, a);
                a = fmaf(k4.y, w4.y, a);
                a = fmaf(k4.z, w4.z, a);
                a = fmaf(k4.w, w4.w, a);
            }
        }
    }

    fold<48>(v, 1);
    fold<24>(v, 2);
    fold<12>(v, 4);
    fold<6>(v, 8);
#pragma unroll
    for (int k = 0; k < 3; ++k) {
        v[k] += __shfl_xor(v[k], 16);
        v[k] += __shfl_xor(v[k], 32);
    }

    if (lane < 16) {
        const int bb  = lane & 7;
        const int rhi = lane >> 3;
#pragma unroll
        for (int k = 0; k < 3; ++k) {
            const int r   = 2 * k + rhi;
            const int idx = (b0 + bb) * N + (i0 + r);
            dst[idx] = src[idx] / v[k];
        }
    }
}

__global__ __launch_bounds__(64, 1) void sk_fused(const float* __restrict__ logits,
                                                  const float* __restrict__ target,
                                                  const float* __restrict__ C,
                                                  float* __restrict__ out,
                                                  int* __restrict__ bar,
                                                  float* __restrict__ partials,
                                                  float* __restrict__ A,
                                                  float* __restrict__ Bh,
                                                  float* __restrict__ P,
                                                  float* __restrict__ Q) {
    const int bid  = blockIdx.x;
    const int lane = threadIdx.x;
    const int h    = bid >= 384 ? 1 : 0;
    const int g    = bid - (h ? 384 : 0);
    const int i0   = g * 6;
    const int b0   = h * 8;
    const int jl   = lane * 4;

    // ---- phase 0: init (blocks 0..15) + K slab into registers -------------
    if (bid < B) {
        float xs[36];
        float m = -3.0e38f;
#pragma unroll
        for (int s = 0; s < 36; ++s) {
            xs[s] = logits[bid * N + s * 64 + lane];
            m = fmaxf(m, xs[s]);
        }
#pragma unroll
        for (int off = 32; off >= 1; off >>= 1) m = fmaxf(m, __shfl_xor(m, off));
        float sum = 0.f;
#pragma unroll
        for (int s = 0; s < 36; ++s) sum += __expf(xs[s] - m);
        sum = wave_sum(sum);
        const float inv = 1.f / sum;
#pragma unroll
        for (int s = 0; s < 36; ++s) {
            const int i = s * 64 + lane;
            P[bid * N + i] = __expf(xs[s] - m) * inv;
            Q[bid * N + i] = target[bid * N + i] + 1e-8f;
        }
    }

    float4 K[6][9];
#pragma unroll
    for (int r = 0; r < 6; ++r)
#pragma unroll
        for (int it = 0; it < 9; ++it)
            K[r][it] = expk4(*(const float4*)(C + (i0 + r) * N + it * 256 + jl));

    gridbar(bar, 1);  // P, Q visible everywhere

    // ---- a1 = P / rowsum(K)  (rowsums straight from registers) ------------
    {
        float s6[6];
#pragma unroll
        for (int r = 0; r < 6; ++r) {
            float t = 0.f;
#pragma unroll
            for (int it = 0; it < 9; ++it) {
                const float4 k4 = K[r][it];
                t += (k4.x + k4.y) + (k4.z + k4.w);
            }
            s6[r] = wave_sum(t);
        }
        if (lane < 8) {
#pragma unroll
            for (int r = 0; r < 6; ++r) {
                const int idx = (b0 + lane) * N + (i0 + r);
                A[idx] = P[idx] / s6[r];
            }
        }
    }
    gridbar(bar, 2);  // A (=a1) ready

    // ---- 19 more scaling passes -------------------------------------------
    for (int t = 0; t < 10; ++t) {
        halfpass(K, A, Q, Bh, i0, b0, jl, lane);   // b_{t+1}
        gridbar(bar, 3 + 2 * t);
        if (t < 9) {
            halfpass(K, Bh, P, A, i0, b0, jl, lane);  // a_{t+2}
            gridbar(bar, 4 + 2 * t);
        }
    }
    // after phase 21: A = a10, Bh = b10

    // ---- cost: partial = sum_{r,b} A[b][i] * sum_j C*K[i][j]*Bh[b][j] -----
    {
        float v[48];
#pragma unroll
        for (int k = 0; k < 48; ++k) v[k] = 0.f;

#pragma unroll
        for (int it = 0; it < 9; ++it) {
            const int j0 = it * 256 + jl;
            float4 wv[8];
#pragma unroll
            for (int bb = 0; bb < 8; ++bb)
                wv[bb] = *(const float4*)(Bh + (b0 + bb) * N + j0);
#pragma unroll
            for (int r = 0; r < 6; ++r) {
                const float4 c4 = *(const float4*)(C + (i0 + r) * N + j0);
                const float4 k4 = K[r][it];
                float4 kc;
                kc.x = k4.x * c4.x;
                kc.y = k4.y * c4.y;
                kc.z = k4.z * c4.z;
                kc.w = k4.w * c4.w;
#pragma unroll
                for (int bb = 0; bb < 8; ++bb) {
                    float& a = v[r * 8 + bb];
                    a = fmaf(kc.x, wv[bb].x, a);
                    a = fmaf(kc.y, wv[bb].y, a);
                    a = fmaf(kc.z, wv[bb].z, a);
                    a = fmaf(kc.w, wv[bb].w, a);
                }
            }
        }

        fold<48>(v, 1);
        fold<24>(v, 2);
        fold<12>(v, 4);
        fold<6>(v, 8);
#pragma unroll
        for (int k = 0; k < 3; ++k) {
            v[k] += __shfl_xor(v[k], 16);
            v[k] += __shfl_xor(v[k], 32);
        }

        // each 16-lane group holds identical sums -> 4x duplication, x0.25
        const int bb  = lane & 7;
        const int rhi = (lane >> 3) & 1;
        float val = 0.f;
#pragma unroll
        for (int k = 0; k < 3; ++k) {
            const int r = 2 * k + rhi;
            val += v[k] * A[(b0 + bb) * N + (i0 + r)];
        }
        val = wave_sum(val) * 0.25f;
        if (lane == 0) partials[bid] = val;
    }

    gridbar(bar, 22);

    if (bid == 0) {
        float t = 0.f;
#pragma unroll
        for (int k = 0; k < 12; ++k) t += partials[lane + 64 * k];
        t = wave_sum(t);
        if (lane == 0) out[0] = t * (1.f / 16.f);
    }
}

}  // namespace

extern "C" void kernel_launch(void* const* d_in, const int* in_sizes, int n_in,
                              void* d_out, int out_size, void* d_ws, size_t ws_size,
                              hipStream_t stream) {
    const float* logits = (const float*)d_in[0];   // (B, 48, 48)
    const float* target = (const float*)d_in[1];   // (B, 48, 48)
    const float* C      = (const float*)d_in[2];   // (1, N, N)
    float* out = (float*)d_out;
    float* ws  = (float*)d_ws;

    int*   bar      = (int*)ws;        // 1024 ints (16 leaves @128B + super)
    float* partials = ws + 1024;       // [768]
    float* A  = ws + 2048;             // [B][N]
    float* Bh = A + NB;                // [B][N]
    float* P  = Bh + NB;               // [B][N]
    float* Q  = P + NB;                // [B][N]

    hipMemsetAsync(bar, 0, 4096, stream);  // zero barrier counters (captured)
    sk_fused<<<768, 64, 0, stream>>>(logits, target, C, out, bar, partials,
                                     A, Bh, P, Q);
}

// Round 5
// 450.912 us; speedup vs baseline: 3.1257x; 3.1257x over previous
//
#include <hip/hip_runtime.h>

// Sinkhorn image loss — persistent kernel, K in LDS (round 4 spilled K-in-regs).
//   p = softmax(pred_logits) ; q = target + 1e-8 ; K = exp(-C/eps), eps=0.01
//   a1 = p / rowsum(K) ; alternate b = q/(K a), a = p/(K b)   (K symmetric)
//   cost_b = sum_ij a_i b_j K_ij C_ij ; out = mean_b
//
// 256 blocks x 256 thr (1 block/CU via 83 KB LDS). Block owns 9 rows x 16
// batches; wave = 9 rows x 4 batches, full j. K slab exp'd once into LDS.
// Every block computes all 16 softmax normalizers locally (redundant, ~1 us)
// so no P/Q arrays and no init barrier; per-block p/q values = 36 scalars in
// regs. Grid sync: 21 hierarchical agent-scope atomic barriers (round-4
// pattern, correctness-proven). Registers ~180/thread — no spill.

namespace {

constexpr int N   = 2304;    // 48*48
constexpr int B   = 16;
constexpr int NB  = N * B;
constexpr int RPB = 9;       // rows per block
constexpr int F4R = N / 4;   // 576 float4 per row

__device__ __forceinline__ float4 expk4(float4 c) {
    float4 k;
    k.x = __expf(c.x * -100.f);
    k.y = __expf(c.y * -100.f);
    k.z = __expf(c.z * -100.f);
    k.w = __expf(c.w * -100.f);
    return k;
}

__device__ __forceinline__ float wave_sum(float v) {
#pragma unroll
    for (int off = 32; off >= 1; off >>= 1) v += __shfl_xor(v, off);
    return v;
}

// online-softmax merge: (m,s) <- merge((m,s),(m2,s2))
__device__ __forceinline__ void ofmerge(float& m, float& s, float m2, float s2) {
    const float mn = fmaxf(m, m2);
    s = s * __expf(m - mn) + s2 * __expf(m2 - mn);
    m = mn;
}

// Fold-reduce (round-3-proven): after folding bits 1,2,4,8 on v[48], slot k
// on lane l holds the 16-lane-group sum of original index 16k + (l&15);
// the +shfl 16,32 then makes it the full-wave sum.
template <int NV>
__device__ __forceinline__ void fold(float* v, int bit) {
    const bool hi = (threadIdx.x & bit) != 0;
#pragma unroll
    for (int k = 0; k < NV / 2; ++k) {
        const float a = hi ? v[2 * k + 1] : v[2 * k];
        const float b = hi ? v[2 * k]     : v[2 * k + 1];
        v[k] = a + __shfl_xor(b, bit);
    }
}

// Grid barrier: 256 blocks, 16 leaves (128 B apart) + super. Monotone counts.
__device__ __forceinline__ void gridbar(int* __restrict__ bar, int phase) {
    __syncthreads();
    if (threadIdx.x == 0) {
        int* leaf  = bar + ((blockIdx.x & 15) << 5);
        int* super = bar + 512;
        const int old = __hip_atomic_fetch_add(leaf, 1, __ATOMIC_ACQ_REL,
                                               __HIP_MEMORY_SCOPE_AGENT);
        if (old == phase * 16 - 1)
            __hip_atomic_fetch_add(super, 1, __ATOMIC_ACQ_REL,
                                   __HIP_MEMORY_SCOPE_AGENT);
        while (__hip_atomic_load(super, __ATOMIC_ACQUIRE,
                                 __HIP_MEMORY_SCOPE_AGENT) < phase * 16)
            __builtin_amdgcn_s_sleep(1);
    }
    __syncthreads();
}

// One scaling pass: dst[b][i] = srcv / sum_j K[i][j] * win[b][j].
// Wave = 9 rows x 4 batches (b0..b0+3), full j; K from LDS, win from global.
__device__ __forceinline__ void halfpass(const float4 (&Kl)[RPB * F4R],
                                         const float* __restrict__ win,
                                         const float (&srcv)[3],
                                         float* __restrict__ dst,
                                         int i0, int b0, int lane) {
    float v[48];
#pragma unroll
    for (int k = 0; k < 48; ++k) v[k] = 0.f;

    float4 kb[2][RPB], wb[2][4];
#pragma unroll
    for (int r = 0; r < RPB; ++r) kb[0][r] = Kl[r * F4R + lane];
#pragma unroll
    for (int bb = 0; bb < 4; ++bb)
        wb[0][bb] = *(const float4*)(win + (b0 + bb) * N + lane * 4);

#pragma unroll
    for (int it = 0; it < 9; ++it) {
        const int cur = it & 1, nxt = cur ^ 1;
        if (it < 8) {  // compile-time after unroll
            const int fi = (it + 1) * 64 + lane;
#pragma unroll
            for (int r = 0; r < RPB; ++r) kb[nxt][r] = Kl[r * F4R + fi];
#pragma unroll
            for (int bb = 0; bb < 4; ++bb)
                wb[nxt][bb] = *(const float4*)(win + (b0 + bb) * N + fi * 4);
        }
#pragma unroll
        for (int r = 0; r < RPB; ++r) {
            const float4 k4 = kb[cur][r];
#pragma unroll
            for (int bb = 0; bb < 4; ++bb) {
                const float4 w4 = wb[cur][bb];
                float& a = v[r * 4 + bb];
                a = fmaf(k4.x, w4.x, a);
                a = fmaf(k4.y, w4.y, a);
                a = fmaf(k4.z, w4.z, a);
                a = fmaf(k4.w, w4.w, a);
            }
        }
    }

    fold<48>(v, 1);
    fold<24>(v, 2);
    fold<12>(v, 4);
    fold<6>(v, 8);
#pragma unroll
    for (int k = 0; k < 3; ++k) {
        v[k] += __shfl_xor(v[k], 16);
        v[k] += __shfl_xor(v[k], 32);
    }

    // slot k, lane l -> idx 16k+(l&15) = r*4+bb : r = 4k+(l>>2), bb = l&3
    if (lane < 16) {
#pragma unroll
        for (int k = 0; k < 3; ++k) {
            const int r = 4 * k + (lane >> 2);
            if (r < RPB) {
                const int idx = (b0 + (lane & 3)) * N + i0 + r;
                dst[idx] = srcv[k] / v[k];
            }
        }
    }
}

__global__ __launch_bounds__(256, 1) void sk_fused(const float* __restrict__ logits,
                                                   const float* __restrict__ target,
                                                   const float* __restrict__ C,
                                                   float* __restrict__ out,
                                                   int* __restrict__ bar,
                                                   float* __restrict__ partials,
                                                   float* __restrict__ A,
                                                   float* __restrict__ Bh) {
    __shared__ float4 Kl[RPB * F4R];          // 82944 B
    __shared__ float  rs[RPB];
    __shared__ float  smx[B][4], ssm[B][4];
    __shared__ float  wval[4];

    const int bid  = blockIdx.x;
    const int tid  = threadIdx.x;
    const int w    = tid >> 6;
    const int lane = tid & 63;
    const int i0   = bid * RPB;
    const int b0   = w * 4;

    // ---- softmax stats for all 16 batches (redundant per block, once) -----
    for (int b = 0; b < B; ++b) {
        float m = -3.0e38f, s = 0.f;
#pragma unroll
        for (int k2 = 0; k2 < 9; ++k2)
            ofmerge(m, s, logits[b * N + k2 * 256 + tid], 1.0f);
#pragma unroll
        for (int off = 32; off >= 1; off >>= 1)
            ofmerge(m, s, __shfl_xor(m, off), __shfl_xor(s, off));
        if (lane == 0) { smx[b][w] = m; ssm[b][w] = s; }
    }

    // ---- K slab: exp(-100*C) -> LDS (once) --------------------------------
#pragma unroll
    for (int r = 0; r < RPB; ++r)
        for (int ct = tid; ct < F4R; ct += 256)
            Kl[r * F4R + ct] = expk4(*(const float4*)(C + (i0 + r) * N + ct * 4));
    __syncthreads();  // Kl + smx/ssm visible block-wide

    // ---- rowsums (wave w -> rows w, w+4, w+8) -----------------------------
    for (int r = w; r < RPB; r += 4) {
        float s = 0.f;
#pragma unroll
        for (int it = 0; it < 9; ++it) {
            const float4 k4 = Kl[r * F4R + it * 64 + lane];
            s += (k4.x + k4.y) + (k4.z + k4.w);
        }
        s = wave_sum(s);
        if (lane == 0) rs[r] = s;
    }

    // ---- per-lane merged softmax + p/q slice (36 scalars per block) -------
    const int bneed = b0 + (lane & 3);
    float sp[3] = {0.f, 0.f, 0.f}, sq[3] = {0.f, 0.f, 0.f};
    {
        float m = smx[bneed][0], s = ssm[bneed][0];
        ofmerge(m, s, smx[bneed][1], ssm[bneed][1]);
        ofmerge(m, s, smx[bneed][2], ssm[bneed][2]);
        ofmerge(m, s, smx[bneed][3], ssm[bneed][3]);
        const float inv = 1.f / s;
        if (lane < 16) {
#pragma unroll
            for (int k = 0; k < 3; ++k) {
                const int r = 4 * k + (lane >> 2);
                if (r < RPB) {
                    sp[k] = __expf(logits[bneed * N + i0 + r] - m) * inv;
                    sq[k] = target[bneed * N + i0 + r] + 1e-8f;
                }
            }
        }
    }
    __syncthreads();  // rs visible

    // ---- a1 = p / rowsum(K) ----------------------------------------------
    if (lane < 16) {
#pragma unroll
        for (int k = 0; k < 3; ++k) {
            const int r = 4 * k + (lane >> 2);
            if (r < RPB) A[bneed * N + i0 + r] = sp[k] / rs[r];
        }
    }
    gridbar(bar, 1);  // A = a1 visible

    // ---- 19 scaling passes ------------------------------------------------
    for (int t = 0; t < 10; ++t) {
        halfpass(Kl, A, sq, Bh, i0, b0, lane);       // b_{t+1}
        gridbar(bar, 2 + 2 * t);
        if (t < 9) {
            halfpass(Kl, Bh, sp, A, i0, b0, lane);   // a_{t+2}
            gridbar(bar, 3 + 2 * t);
        }
    }
    // barriers used: 1..20 ; A = a10, Bh = b10

    // ---- cost: partial = sum_{r,b} A[b][i] * sum_j C*K[i][j] * Bh[b][j] ---
    {
        float v[48];
#pragma unroll
        for (int k = 0; k < 48; ++k) v[k] = 0.f;

        float4 cb[2][RPB], wb[2][4];
#pragma unroll
        for (int r = 0; r < RPB; ++r)
            cb[0][r] = *(const float4*)(C + (i0 + r) * N + lane * 4);
#pragma unroll
        for (int bb = 0; bb < 4; ++bb)
            wb[0][bb] = *(const float4*)(Bh + (b0 + bb) * N + lane * 4);

#pragma unroll
        for (int it = 0; it < 9; ++it) {
            const int cur = it & 1, nxt = cur ^ 1;
            if (it < 8) {
                const int fi = (it + 1) * 64 + lane;
#pragma unroll
                for (int r = 0; r < RPB; ++r)
                    cb[nxt][r] = *(const float4*)(C + (i0 + r) * N + fi * 4);
#pragma unroll
                for (int bb = 0; bb < 4; ++bb)
                    wb[nxt][bb] = *(const float4*)(Bh + (b0 + bb) * N + fi * 4);
            }
#pragma unroll
            for (int r = 0; r < RPB; ++r) {
                const float4 k4 = Kl[r * F4R + it * 64 + lane];
                const float4 c4 = cb[cur][r];
                float4 kc;
                kc.x = k4.x * c4.x;
                kc.y = k4.y * c4.y;
                kc.z = k4.z * c4.z;
                kc.w = k4.w * c4.w;
#pragma unroll
                for (int bb = 0; bb < 4; ++bb) {
                    const float4 w4 = wb[cur][bb];
                    float& a = v[r * 4 + bb];
                    a = fmaf(kc.x, w4.x, a);
                    a = fmaf(kc.y, w4.y, a);
                    a = fmaf(kc.z, w4.z, a);
                    a = fmaf(kc.w, w4.w, a);
                }
            }
        }

        fold<48>(v, 1);
        fold<24>(v, 2);
        fold<12>(v, 4);
        fold<6>(v, 8);
#pragma unroll
        for (int k = 0; k < 3; ++k) {
            v[k] += __shfl_xor(v[k], 16);
            v[k] += __shfl_xor(v[k], 32);
        }

        // dot with a-hat; all 64 lanes -> 4x duplication, scale 0.25
        float val = 0.f;
#pragma unroll
        for (int k = 0; k < 3; ++k) {
            const int r = 4 * k + ((lane & 15) >> 2);
            if (r < RPB)
                val += v[k] * A[(b0 + (lane & 3)) * N + i0 + r];
        }
        val = wave_sum(val) * 0.25f;
        if (lane == 0) wval[w] = val;
        __syncthreads();
        if (tid == 0)
            partials[bid] = wval[0] + wval[1] + wval[2] + wval[3];
    }

    gridbar(bar, 21);

    if (bid == 0 && tid < 64) {
        float t = partials[tid] + partials[tid + 64] +
                  partials[tid + 128] + partials[tid + 192];
        t = wave_sum(t);
        if (tid == 0) out[0] = t * (1.f / 16.f);
    }
}

}  // namespace

extern "C" void kernel_launch(void* const* d_in, const int* in_sizes, int n_in,
                              void* d_out, int out_size, void* d_ws, size_t ws_size,
                              hipStream_t stream) {
    const float* logits = (const float*)d_in[0];   // (B, 48, 48)
    const float* target = (const float*)d_in[1];   // (B, 48, 48)
    const float* C      = (const float*)d_in[2];   // (1, N, N)
    float* out = (float*)d_out;
    float* ws  = (float*)d_ws;

    int*   bar      = (int*)ws;          // 1024 ints: 16 leaves @128B + super
    float* partials = ws + 1024;         // [256]
    float* A  = ws + 1024 + 256;         // [B][N]
    float* Bh = A + NB;                  // [B][N]

    hipMemsetAsync(bar, 0, 4096, stream);  // zero barrier counters (captured)
    sk_fused<<<256, 256, 0, stream>>>(logits, target, C, out, bar, partials,
                                      A, Bh);
}

// Round 6
// 296.023 us; speedup vs baseline: 4.7612x; 1.5232x over previous
//
#include <hip/hip_runtime.h>

// Sinkhorn image loss — persistent kernel, K in LDS, CHEAP grid barrier.
//   p = softmax(pred_logits) ; q = target + 1e-8 ; K = exp(-C/eps), eps=0.01
//   a1 = p / rowsum(K) ; alternate b = q/(K a), a = p/(K b)   (K symmetric)
//   cost_b = sum_ij a_i b_j K_ij C_ij ; out = mean_b
//
// 256 blocks x 256 thr (1 block/CU via 83 KB LDS). Block owns 9 rows x 16
// batches; wave = 9 rows x 4 batches, full j. K slab exp'd once into LDS.
// Round-5 post-mortem: ACQ_REL arrival RMW + ACQUIRE spin loads put L2
// writeback/invalidate on EVERY access -> ~20 us/barrier. Now: ONE release
// fence (wbl2) before arrival, RELAXED RMW + RELAXED spin, ONE acquire
// fence (inv) after -> cache maintenance once per block per barrier.

namespace {

constexpr int N   = 2304;    // 48*48
constexpr int B   = 16;
constexpr int NB  = N * B;
constexpr int RPB = 9;       // rows per block
constexpr int F4R = N / 4;   // 576 float4 per row

__device__ __forceinline__ float4 expk4(float4 c) {
    float4 k;
    k.x = __expf(c.x * -100.f);
    k.y = __expf(c.y * -100.f);
    k.z = __expf(c.z * -100.f);
    k.w = __expf(c.w * -100.f);
    return k;
}

__device__ __forceinline__ float wave_sum(float v) {
#pragma unroll
    for (int off = 32; off >= 1; off >>= 1) v += __shfl_xor(v, off);
    return v;
}

// online-softmax merge: (m,s) <- merge((m,s),(m2,s2))
__device__ __forceinline__ void ofmerge(float& m, float& s, float m2, float s2) {
    const float mn = fmaxf(m, m2);
    s = s * __expf(m - mn) + s2 * __expf(m2 - mn);
    m = mn;
}

// Fold-reduce (round-3-proven): after folding bits 1,2,4,8 on v[48], slot k
// on lane l holds the 16-lane-group sum of original index 16k + (l&15);
// the +shfl 16,32 then makes it the full-wave sum.
template <int NV>
__device__ __forceinline__ void fold(float* v, int bit) {
    const bool hi = (threadIdx.x & bit) != 0;
#pragma unroll
    for (int k = 0; k < NV / 2; ++k) {
        const float a = hi ? v[2 * k + 1] : v[2 * k];
        const float b = hi ? v[2 * k]     : v[2 * k + 1];
        v[k] = a + __shfl_xor(b, bit);
    }
}

// Grid barrier: 256 blocks, 16 leaves (128 B apart) + super. Monotone counts.
// One release fence (s_waitcnt + buffer_wbl2) before arrival, RELAXED RMWs,
// RELAXED spin, one acquire fence (buffer_inv) after release observed.
__device__ __forceinline__ void gridbar(int* __restrict__ bar, int phase) {
    __syncthreads();  // all 4 waves' stores drained to L2 (vmcnt 0)
    if (threadIdx.x == 0) {
        __builtin_amdgcn_fence(__ATOMIC_RELEASE, "agent");   // wbl2 once
        int* leaf  = bar + ((blockIdx.x & 15) << 5);
        int* super = bar + 512;
        const int old = __hip_atomic_fetch_add(leaf, 1, __ATOMIC_RELAXED,
                                               __HIP_MEMORY_SCOPE_AGENT);
        if (old == phase * 16 - 1)
            __hip_atomic_fetch_add(super, 1, __ATOMIC_RELAXED,
                                   __HIP_MEMORY_SCOPE_AGENT);
        while (__hip_atomic_load(super, __ATOMIC_RELAXED,
                                 __HIP_MEMORY_SCOPE_AGENT) < phase * 16)
            __builtin_amdgcn_s_sleep(2);
        __builtin_amdgcn_fence(__ATOMIC_ACQUIRE, "agent");   // inv once
    }
    __syncthreads();  // CU-wide: waves 1-3 blocked until inv done
}

// One scaling pass: dst[b][i] = srcv / sum_j K[i][j] * win[b][j].
// Wave = 9 rows x 4 batches (b0..b0+3), full j; K from LDS, win from global.
__device__ __forceinline__ void halfpass(const float4 (&Kl)[RPB * F4R],
                                         const float* __restrict__ win,
                                         const float (&srcv)[3],
                                         float* __restrict__ dst,
                                         int i0, int b0, int lane) {
    float v[48];
#pragma unroll
    for (int k = 0; k < 48; ++k) v[k] = 0.f;

    float4 kb[2][RPB], wb[2][4];
#pragma unroll
    for (int r = 0; r < RPB; ++r) kb[0][r] = Kl[r * F4R + lane];
#pragma unroll
    for (int bb = 0; bb < 4; ++bb)
        wb[0][bb] = *(const float4*)(win + (b0 + bb) * N + lane * 4);

#pragma unroll
    for (int it = 0; it < 9; ++it) {
        const int cur = it & 1, nxt = cur ^ 1;
        if (it < 8) {  // compile-time after unroll
            const int fi = (it + 1) * 64 + lane;
#pragma unroll
            for (int r = 0; r < RPB; ++r) kb[nxt][r] = Kl[r * F4R + fi];
#pragma unroll
            for (int bb = 0; bb < 4; ++bb)
                wb[nxt][bb] = *(const float4*)(win + (b0 + bb) * N + fi * 4);
        }
#pragma unroll
        for (int r = 0; r < RPB; ++r) {
            const float4 k4 = kb[cur][r];
#pragma unroll
            for (int bb = 0; bb < 4; ++bb) {
                const float4 w4 = wb[cur][bb];
                float& a = v[r * 4 + bb];
                a = fmaf(k4.x, w4.x, a);
                a = fmaf(k4.y, w4.y, a);
                a = fmaf(k4.z, w4.z, a);
                a = fmaf(k4.w, w4.w, a);
            }
        }
    }

    fold<48>(v, 1);
    fold<24>(v, 2);
    fold<12>(v, 4);
    fold<6>(v, 8);
#pragma unroll
    for (int k = 0; k < 3; ++k) {
        v[k] += __shfl_xor(v[k], 16);
        v[k] += __shfl_xor(v[k], 32);
    }

    // slot k, lane l -> idx 16k+(l&15) = r*4+bb : r = 4k+(l>>2), bb = l&3
    if (lane < 16) {
#pragma unroll
        for (int k = 0; k < 3; ++k) {
            const int r = 4 * k + (lane >> 2);
            if (r < RPB) {
                const int idx = (b0 + (lane & 3)) * N + i0 + r;
                dst[idx] = srcv[k] / v[k];
            }
        }
    }
}

__global__ __launch_bounds__(256, 1) void sk_fused(const float* __restrict__ logits,
                                                   const float* __restrict__ target,
                                                   const float* __restrict__ C,
                                                   float* __restrict__ out,
                                                   int* __restrict__ bar,
                                                   float* __restrict__ partials,
                                                   float* __restrict__ A,
                                                   float* __restrict__ Bh) {
    __shared__ float4 Kl[RPB * F4R];          // 82944 B
    __shared__ float  rs[RPB];
    __shared__ float  smx[B][4], ssm[B][4];
    __shared__ float  wval[4];

    const int bid  = blockIdx.x;
    const int tid  = threadIdx.x;
    const int w    = tid >> 6;
    const int lane = tid & 63;
    const int i0   = bid * RPB;
    const int b0   = w * 4;

    // ---- softmax stats for all 16 batches (redundant per block, once) -----
    for (int b = 0; b < B; ++b) {
        float m = -3.0e38f, s = 0.f;
#pragma unroll
        for (int k2 = 0; k2 < 9; ++k2)
            ofmerge(m, s, logits[b * N + k2 * 256 + tid], 1.0f);
#pragma unroll
        for (int off = 32; off >= 1; off >>= 1)
            ofmerge(m, s, __shfl_xor(m, off), __shfl_xor(s, off));
        if (lane == 0) { smx[b][w] = m; ssm[b][w] = s; }
    }

    // ---- K slab: exp(-100*C) -> LDS (once) --------------------------------
#pragma unroll
    for (int r = 0; r < RPB; ++r)
        for (int ct = tid; ct < F4R; ct += 256)
            Kl[r * F4R + ct] = expk4(*(const float4*)(C + (i0 + r) * N + ct * 4));
    __syncthreads();  // Kl + smx/ssm visible block-wide

    // ---- rowsums (wave w -> rows w, w+4, w+8) -----------------------------
    for (int r = w; r < RPB; r += 4) {
        float s = 0.f;
#pragma unroll
        for (int it = 0; it < 9; ++it) {
            const float4 k4 = Kl[r * F4R + it * 64 + lane];
            s += (k4.x + k4.y) + (k4.z + k4.w);
        }
        s = wave_sum(s);
        if (lane == 0) rs[r] = s;
    }

    // ---- per-lane merged softmax + p/q slice (36 scalars per block) -------
    const int bneed = b0 + (lane & 3);
    float sp[3] = {0.f, 0.f, 0.f}, sq[3] = {0.f, 0.f, 0.f};
    {
        float m = smx[bneed][0], s = ssm[bneed][0];
        ofmerge(m, s, smx[bneed][1], ssm[bneed][1]);
        ofmerge(m, s, smx[bneed][2], ssm[bneed][2]);
        ofmerge(m, s, smx[bneed][3], ssm[bneed][3]);
        const float inv = 1.f / s;
        if (lane < 16) {
#pragma unroll
            for (int k = 0; k < 3; ++k) {
                const int r = 4 * k + (lane >> 2);
                if (r < RPB) {
                    sp[k] = __expf(logits[bneed * N + i0 + r] - m) * inv;
                    sq[k] = target[bneed * N + i0 + r] + 1e-8f;
                }
            }
        }
    }
    __syncthreads();  // rs visible

    // ---- a1 = p / rowsum(K) ----------------------------------------------
    if (lane < 16) {
#pragma unroll
        for (int k = 0; k < 3; ++k) {
            const int r = 4 * k + (lane >> 2);
            if (r < RPB) A[bneed * N + i0 + r] = sp[k] / rs[r];
        }
    }
    gridbar(bar, 1);  // A = a1 visible

    // ---- 19 scaling passes ------------------------------------------------
    for (int t = 0; t < 10; ++t) {
        halfpass(Kl, A, sq, Bh, i0, b0, lane);       // b_{t+1}
        gridbar(bar, 2 + 2 * t);
        if (t < 9) {
            halfpass(Kl, Bh, sp, A, i0, b0, lane);   // a_{t+2}
            gridbar(bar, 3 + 2 * t);
        }
    }
    // barriers used: 1..20 ; A = a10, Bh = b10

    // ---- cost: partial = sum_{r,b} A[b][i] * sum_j C*K[i][j] * Bh[b][j] ---
    {
        float v[48];
#pragma unroll
        for (int k = 0; k < 48; ++k) v[k] = 0.f;

        float4 cb[2][RPB], wb[2][4];
#pragma unroll
        for (int r = 0; r < RPB; ++r)
            cb[0][r] = *(const float4*)(C + (i0 + r) * N + lane * 4);
#pragma unroll
        for (int bb = 0; bb < 4; ++bb)
            wb[0][bb] = *(const float4*)(Bh + (b0 + bb) * N + lane * 4);

#pragma unroll
        for (int it = 0; it < 9; ++it) {
            const int cur = it & 1, nxt = cur ^ 1;
            if (it < 8) {
                const int fi = (it + 1) * 64 + lane;
#pragma unroll
                for (int r = 0; r < RPB; ++r)
                    cb[nxt][r] = *(const float4*)(C + (i0 + r) * N + fi * 4);
#pragma unroll
                for (int bb = 0; bb < 4; ++bb)
                    wb[nxt][bb] = *(const float4*)(Bh + (b0 + bb) * N + fi * 4);
            }
#pragma unroll
            for (int r = 0; r < RPB; ++r) {
                const float4 k4 = Kl[r * F4R + it * 64 + lane];
                const float4 c4 = cb[cur][r];
                float4 kc;
                kc.x = k4.x * c4.x;
                kc.y = k4.y * c4.y;
                kc.z = k4.z * c4.z;
                kc.w = k4.w * c4.w;
#pragma unroll
                for (int bb = 0; bb < 4; ++bb) {
                    const float4 w4 = wb[cur][bb];
                    float& a = v[r * 4 + bb];
                    a = fmaf(kc.x, w4.x, a);
                    a = fmaf(kc.y, w4.y, a);
                    a = fmaf(kc.z, w4.z, a);
                    a = fmaf(kc.w, w4.w, a);
                }
            }
        }

        fold<48>(v, 1);
        fold<24>(v, 2);
        fold<12>(v, 4);
        fold<6>(v, 8);
#pragma unroll
        for (int k = 0; k < 3; ++k) {
            v[k] += __shfl_xor(v[k], 16);
            v[k] += __shfl_xor(v[k], 32);
        }

        // dot with a-hat; all 64 lanes -> 4x duplication, scale 0.25
        float val = 0.f;
#pragma unroll
        for (int k = 0; k < 3; ++k) {
            const int r = 4 * k + ((lane & 15) >> 2);
            if (r < RPB)
                val += v[k] * A[(b0 + (lane & 3)) * N + i0 + r];
        }
        val = wave_sum(val) * 0.25f;
        if (lane == 0) wval[w] = val;
        __syncthreads();
        if (tid == 0)
            partials[bid] = wval[0] + wval[1] + wval[2] + wval[3];
    }

    gridbar(bar, 21);

    if (bid == 0 && tid < 64) {
        float t = partials[tid] + partials[tid + 64] +
                  partials[tid + 128] + partials[tid + 192];
        t = wave_sum(t);
        if (tid == 0) out[0] = t * (1.f / 16.f);
    }
}

}  // namespace

extern "C" void kernel_launch(void* const* d_in, const int* in_sizes, int n_in,
                              void* d_out, int out_size, void* d_ws, size_t ws_size,
                              hipStream_t stream) {
    const float* logits = (const float*)d_in[0];   // (B, 48, 48)
    const float* target = (const float*)d_in[1];   // (B, 48, 48)
    const float* C      = (const float*)d_in[2];   // (1, N, N)
    float* out = (float*)d_out;
    float* ws  = (float*)d_ws;

    int*   bar      = (int*)ws;          // 1024 ints: 16 leaves @128B + super
    float* partials = ws + 1024;         // [256]
    float* A  = ws + 1024 + 256;         // [B][N]
    float* Bh = A + NB;                  // [B][N]

    hipMemsetAsync(bar, 0, 4096, stream);  // zero barrier counters (captured)
    sk_fused<<<256, 256, 0, stream>>>(logits, target, C, out, bar, partials,
                                      A, Bh);
}

// Round 8
// 179.474 us; speedup vs baseline: 7.8531x; 1.6494x over previous
//
#include <hip/hip_runtime.h>

// Sinkhorn image loss — multi-kernel (deadlock-free), fat 256x256 pass kernels.
//   p = softmax(pred_logits) ; q = target + 1e-8 ; K = exp(-C/eps), eps=0.01
//   a1 = p / rowsum(K) ; alternate b = q/(K a), a = p/(K b)   (K symmetric)
//   cost = mean_b sum_j b10_j * (K.C a10)_j,  b10 = q/(K a10)  [b10 fused]
//
// Pass kernel: 256 blocks x 256 thr (1 block/CU). Block owns 9 rows x 16
// batches; wave = 9 rows x 4 batches, full j (round-5/6-proven v[48]
// partition + register double-buffer, ~180 VGPR). sk_first uses the SAME
// bid->rows mapping, so each K row is written and re-read by the same XCD:
// K stays L2-resident per XCD (2.65 MB < 4 MB) across all passes.
// Cross-kernel visibility of the dual vectors = implicit dispatch-boundary
// release/acquire. No spin barriers anywhere.

namespace {

constexpr int N   = 2304;    // 48*48
constexpr int B   = 16;
constexpr int NB  = N * B;
constexpr int RPB = 9;       // rows per block

__device__ __forceinline__ float4 expk4(float4 c) {
    float4 k;
    k.x = __expf(c.x * -100.f);
    k.y = __expf(c.y * -100.f);
    k.z = __expf(c.z * -100.f);
    k.w = __expf(c.w * -100.f);
    return k;
}

__device__ __forceinline__ float wave_sum(float v) {
#pragma unroll
    for (int off = 32; off >= 1; off >>= 1) v += __shfl_xor(v, off);
    return v;
}

// Fold-reduce (round-3/5/6-proven): after folding bits 1,2,4,8 on v[48],
// slot k on lane l holds the 16-lane-group sum of original index 16k+(l&15);
// +shfl 16,32 makes it the full-wave sum. idx 16k+(l&15) = r*4+bb with
// r = 4k+((l&15)>>2), bb = l&3.
template <int NV>
__device__ __forceinline__ void fold(float* v, int bit) {
    const bool hi = (threadIdx.x & bit) != 0;
#pragma unroll
    for (int k = 0; k < NV / 2; ++k) {
        const float a = hi ? v[2 * k + 1] : v[2 * k];
        const float b = hi ? v[2 * k]     : v[2 * k + 1];
        v[k] = a + __shfl_xor(b, bit);
    }
}

__device__ __forceinline__ void fold48(float* v) {
    fold<48>(v, 1);
    fold<24>(v, 2);
    fold<12>(v, 4);
    fold<6>(v, 8);
#pragma unroll
    for (int k = 0; k < 3; ++k) {
        v[k] += __shfl_xor(v[k], 16);
        v[k] += __shfl_xor(v[k], 32);
    }
}

// ---------------------------------------------------------------- init ----
// One block per batch: P = softmax(logits), Q = target + 1e-8; zero out.
__global__ __launch_bounds__(256) void sk_init(const float* __restrict__ logits,
                                               const float* __restrict__ target,
                                               float* __restrict__ P,
                                               float* __restrict__ Q,
                                               float* __restrict__ out) {
    const int b = blockIdx.x;
    const int t = threadIdx.x;

    float xs[9];
    float m = -3.0e38f;
#pragma unroll
    for (int s = 0; s < 9; ++s) {
        xs[s] = logits[b * N + s * 256 + t];
        m = fmaxf(m, xs[s]);
    }
#pragma unroll
    for (int off = 32; off >= 1; off >>= 1) m = fmaxf(m, __shfl_xor(m, off));

    __shared__ float sm[4], ss[4];
    const int w = t >> 6;
    if ((t & 63) == 0) sm[w] = m;
    __syncthreads();
    m = fmaxf(fmaxf(sm[0], sm[1]), fmaxf(sm[2], sm[3]));

    float sum = 0.f;
#pragma unroll
    for (int s = 0; s < 9; ++s) sum += __expf(xs[s] - m);
#pragma unroll
    for (int off = 32; off >= 1; off >>= 1) sum += __shfl_xor(sum, off);
    if ((t & 63) == 0) ss[w] = sum;
    __syncthreads();
    sum = ss[0] + ss[1] + ss[2] + ss[3];
    const float inv = 1.f / sum;

#pragma unroll
    for (int s = 0; s < 9; ++s) {
        const int i = s * 256 + t;
        P[b * N + i] = __expf(xs[s] - m) * inv;
        Q[b * N + i] = target[b * N + i] + 1e-8f;
    }
    if (b == 0 && t == 0) out[0] = 0.f;
}

// --------------------------------------------------- first a-update -------
// 256 blocks x 256 thr, SAME 9-row ownership as sk_pass: K = exp(-100C)
// written XCD-local; rowsums; A[b][i] = P[b][i]/rowsum_i for all 16 b.
// Wave w handles rows {w, w+4, w+8} (guard r<9).
__global__ __launch_bounds__(256) void sk_first(const float* __restrict__ C,
                                                float* __restrict__ K,
                                                const float* __restrict__ P,
                                                float* __restrict__ A) {
    __shared__ float rs[RPB];
    const int bid  = blockIdx.x;
    const int tid  = threadIdx.x;
    const int w    = tid >> 6;
    const int lane = tid & 63;
    const int i0   = bid * RPB;
    const int b0   = w * 4;

    for (int r = w; r < RPB; r += 4) {
        const int row = (i0 + r) * N;
        float s = 0.f;
#pragma unroll
        for (int it = 0; it < 9; ++it) {
            const int off = row + it * 256 + lane * 4;
            const float4 k4 = expk4(*(const float4*)(C + off));
            *(float4*)(K + off) = k4;
            s += (k4.x + k4.y) + (k4.z + k4.w);
        }
        s = wave_sum(s);
        if (lane == 0) rs[r] = s;
    }
    __syncthreads();

    if (lane < 16) {
#pragma unroll
        for (int k = 0; k < 3; ++k) {
            const int r = 4 * k + (lane >> 2);
            if (r < RPB) {
                const int idx = (b0 + (lane & 3)) * N + i0 + r;
                A[idx] = P[idx] / rs[r];
            }
        }
    }
}

// ----------------------------------------------------------- half-pass ----
// dst[b][i] = src[b][i] / sum_j K[i][j] * win[b][j]
// 256 blocks x 256 thr; wave = 9 rows x 4 batches, full j, reg double-buffer.
__global__ __launch_bounds__(256) void sk_pass(const float* __restrict__ K,
                                               const float* __restrict__ win,
                                               const float* __restrict__ src,
                                               float* __restrict__ dst) {
    const int bid  = blockIdx.x;
    const int tid  = threadIdx.x;
    const int w    = tid >> 6;
    const int lane = tid & 63;
    const int i0   = bid * RPB;
    const int b0   = w * 4;

    // src slice (36 scalars per block; 3 per low lane)
    float sv[3] = {0.f, 0.f, 0.f};
    if (lane < 16) {
#pragma unroll
        for (int k = 0; k < 3; ++k) {
            const int r = 4 * k + (lane >> 2);
            if (r < RPB) sv[k] = src[(b0 + (lane & 3)) * N + i0 + r];
        }
    }

    float v[48];
#pragma unroll
    for (int k = 0; k < 48; ++k) v[k] = 0.f;

    float4 kb[2][RPB], wb[2][4];
#pragma unroll
    for (int r = 0; r < RPB; ++r)
        kb[0][r] = *(const float4*)(K + (i0 + r) * N + lane * 4);
#pragma unroll
    for (int bb = 0; bb < 4; ++bb)
        wb[0][bb] = *(const float4*)(win + (b0 + bb) * N + lane * 4);

#pragma unroll
    for (int it = 0; it < 9; ++it) {
        const int cur = it & 1, nxt = cur ^ 1;
        if (it < 8) {  // compile-time after unroll
            const int j0 = (it + 1) * 256 + lane * 4;
#pragma unroll
            for (int r = 0; r < RPB; ++r)
                kb[nxt][r] = *(const float4*)(K + (i0 + r) * N + j0);
#pragma unroll
            for (int bb = 0; bb < 4; ++bb)
                wb[nxt][bb] = *(const float4*)(win + (b0 + bb) * N + j0);
        }
#pragma unroll
        for (int r = 0; r < RPB; ++r) {
            const float4 k4 = kb[cur][r];
#pragma unroll
            for (int bb = 0; bb < 4; ++bb) {
                const float4 w4 = wb[cur][bb];
                float& a = v[r * 4 + bb];
                a = fmaf(k4.x, w4.x, a);
                a = fmaf(k4.y, w4.y, a);
                a = fmaf(k4.z, w4.z, a);
                a = fmaf(k4.w, w4.w, a);
            }
        }
    }

    fold48(v);

    if (lane < 16) {
#pragma unroll
        for (int k = 0; k < 3; ++k) {
            const int r = 4 * k + (lane >> 2);
            if (r < RPB) {
                const int idx = (b0 + (lane & 3)) * N + i0 + r;
                dst[idx] = sv[k] / v[k];
            }
        }
    }
}

// ------------------------------------------------------- fused b10+cost ---
// Per owned row j: s1_j = (K a10)_j, s2_j = (K.C a10)_j; contribution
// q_j/s1_j * s2_j summed over rows x batches; atomicAdd block partial /16.
__global__ __launch_bounds__(256) void sk_cost(const float* __restrict__ K,
                                               const float* __restrict__ C,
                                               const float* __restrict__ A,
                                               const float* __restrict__ Q,
                                               float* __restrict__ out) {
    __shared__ float wval[4];
    const int bid  = blockIdx.x;
    const int tid  = threadIdx.x;
    const int w    = tid >> 6;
    const int lane = tid & 63;
    const int i0   = bid * RPB;
    const int b0   = w * 4;

    float v1[48], v2[48];
#pragma unroll
    for (int k = 0; k < 48; ++k) { v1[k] = 0.f; v2[k] = 0.f; }

#pragma unroll
    for (int it = 0; it < 9; ++it) {
        const int j0 = it * 256 + lane * 4;
        float4 w4[4];
#pragma unroll
        for (int bb = 0; bb < 4; ++bb)
            w4[bb] = *(const float4*)(A + (b0 + bb) * N + j0);
#pragma unroll
        for (int r = 0; r < RPB; ++r) {
            const float4 k4 = *(const float4*)(K + (i0 + r) * N + j0);
            const float4 c4 = *(const float4*)(C + (i0 + r) * N + j0);
            float4 kc;
            kc.x = k4.x * c4.x;
            kc.y = k4.y * c4.y;
            kc.z = k4.z * c4.z;
            kc.w = k4.w * c4.w;
#pragma unroll
            for (int bb = 0; bb < 4; ++bb) {
                float& a1 = v1[r * 4 + bb];
                float& a2 = v2[r * 4 + bb];
                a1 = fmaf(k4.x, w4[bb].x, a1);
                a1 = fmaf(k4.y, w4[bb].y, a1);
                a1 = fmaf(k4.z, w4[bb].z, a1);
                a1 = fmaf(k4.w, w4[bb].w, a1);
                a2 = fmaf(kc.x, w4[bb].x, a2);
                a2 = fmaf(kc.y, w4[bb].y, a2);
                a2 = fmaf(kc.z, w4[bb].z, a2);
                a2 = fmaf(kc.w, w4[bb].w, a2);
            }
        }
    }

    fold48(v1);
    fold48(v2);

    // all 64 lanes: each 16-lane group duplicates -> scale 0.25
    float val = 0.f;
#pragma unroll
    for (int k = 0; k < 3; ++k) {
        const int r = 4 * k + ((lane & 15) >> 2);
        if (r < RPB) {
            const float qv = Q[(b0 + (lane & 3)) * N + i0 + r];
            val += qv / v1[k] * v2[k];
        }
    }
    val = wave_sum(val) * 0.25f;
    if (lane == 0) wval[w] = val;
    __syncthreads();
    if (tid == 0)
        atomicAdd(out, (wval[0] + wval[1] + wval[2] + wval[3]) * (1.f / 16.f));
}

}  // namespace

extern "C" void kernel_launch(void* const* d_in, const int* in_sizes, int n_in,
                              void* d_out, int out_size, void* d_ws, size_t ws_size,
                              hipStream_t stream) {
    const float* logits = (const float*)d_in[0];   // (B, 48, 48)
    const float* target = (const float*)d_in[1];   // (B, 48, 48)
    const float* C      = (const float*)d_in[2];   // (1, N, N)
    float* out = (float*)d_out;
    float* ws  = (float*)d_ws;

    float* A  = ws;                   // [B][N] a-hat
    float* Bh = A + NB;               // [B][N] b-hat
    float* P  = Bh + NB;              // [B][N]
    float* Q  = P + NB;               // [B][N]
    float* K  = Q + NB;               // [N][N]

    sk_init<<<B, 256, 0, stream>>>(logits, target, P, Q, out);
    sk_first<<<256, 256, 0, stream>>>(C, K, P, A);           // K + a1

    // b1..b9 and a2..a10 (18 passes); b10 fused into sk_cost
    for (int t = 1; t <= 9; ++t) {
        sk_pass<<<256, 256, 0, stream>>>(K, A, Q, Bh);       // b_t
        sk_pass<<<256, 256, 0, stream>>>(K, Bh, P, A);       // a_{t+1}
    }

    sk_cost<<<256, 256, 0, stream>>>(K, C, A, Q, out);
}

// Round 9
// 167.595 us; speedup vs baseline: 8.4097x; 1.0709x over previous
//
#include <hip/hip_runtime.h>

// Sinkhorn image loss — multi-kernel (deadlock-free), LDS-staged K passes.
//   p = softmax(pred_logits) ; q = target + 1e-8 ; K = exp(-C/eps), eps=0.01
//   a1 = p / rowsum(K) ; alternate b = q/(K a), a = p/(K b)   (K symmetric)
//   cost = mean_b sum_j b10_j * (K.C a10)_j,  b10 = q/(K a10)  [b10 fused]
//
// Pass kernel: 256 blocks x 256 thr (1 block/CU via 83 KB LDS). Block owns
// 9 rows x 16 batches; wave = 9 rows x 4 batches, full j (v[48] partition,
// round-3..8-proven). NEW vs round 8:
//   * block stages its 9 K-rows into LDS once -> kills the 4x per-wave K
//     duplication (84 MB -> 21 MB device L2 traffic per pass), K reads move
//     to the LDS pipe (~12cyc) off the contended L2 path.
//   * win prefetch depth 2 (wb[3], static idx under full unroll) -> 576 cyc
//     of latency cover for L3-distance win lines (dispatch-inv'd every pass).
// Cross-kernel visibility = implicit dispatch-boundary release/acquire.

namespace {

constexpr int N   = 2304;    // 48*48
constexpr int B   = 16;
constexpr int NB  = N * B;
constexpr int RPB = 9;       // rows per block
constexpr int F4R = N / 4;   // 576 float4 per row
constexpr int KF4 = RPB * F4R;  // 5184 float4 = 82944 B

__device__ __forceinline__ float4 expk4(float4 c) {
    float4 k;
    k.x = __expf(c.x * -100.f);
    k.y = __expf(c.y * -100.f);
    k.z = __expf(c.z * -100.f);
    k.w = __expf(c.w * -100.f);
    return k;
}

__device__ __forceinline__ float wave_sum(float v) {
#pragma unroll
    for (int off = 32; off >= 1; off >>= 1) v += __shfl_xor(v, off);
    return v;
}

// Fold-reduce (round-3..8-proven): after folding bits 1,2,4,8 on v[48],
// slot k on lane l holds the 16-lane-group sum of original index 16k+(l&15);
// +shfl 16,32 makes it the full-wave sum. idx 16k+(l&15) = r*4+bb with
// r = 4k+((l&15)>>2), bb = l&3.
template <int NV>
__device__ __forceinline__ void fold(float* v, int bit) {
    const bool hi = (threadIdx.x & bit) != 0;
#pragma unroll
    for (int k = 0; k < NV / 2; ++k) {
        const float a = hi ? v[2 * k + 1] : v[2 * k];
        const float b = hi ? v[2 * k]     : v[2 * k + 1];
        v[k] = a + __shfl_xor(b, bit);
    }
}

__device__ __forceinline__ void fold48(float* v) {
    fold<48>(v, 1);
    fold<24>(v, 2);
    fold<12>(v, 4);
    fold<6>(v, 8);
#pragma unroll
    for (int k = 0; k < 3; ++k) {
        v[k] += __shfl_xor(v[k], 16);
        v[k] += __shfl_xor(v[k], 32);
    }
}

// Cooperative, coalesced K-slab copy into LDS (9 rows = 5184 float4).
__device__ __forceinline__ void stageK(float4* Kl, const float* K, int i0) {
    const float4* Kg = (const float4*)(K + i0 * N);
    const int tid = threadIdx.x;
#pragma unroll
    for (int k = 0; k < 20; ++k) Kl[tid + k * 256] = Kg[tid + k * 256];
    if (tid < 64) Kl[5120 + tid] = Kg[5120 + tid];
}

// ---------------------------------------------------------------- init ----
// One block per batch: P = softmax(logits), Q = target + 1e-8; zero out.
__global__ __launch_bounds__(256) void sk_init(const float* __restrict__ logits,
                                               const float* __restrict__ target,
                                               float* __restrict__ P,
                                               float* __restrict__ Q,
                                               float* __restrict__ out) {
    const int b = blockIdx.x;
    const int t = threadIdx.x;

    float xs[9];
    float m = -3.0e38f;
#pragma unroll
    for (int s = 0; s < 9; ++s) {
        xs[s] = logits[b * N + s * 256 + t];
        m = fmaxf(m, xs[s]);
    }
#pragma unroll
    for (int off = 32; off >= 1; off >>= 1) m = fmaxf(m, __shfl_xor(m, off));

    __shared__ float sm[4], ss[4];
    const int w = t >> 6;
    if ((t & 63) == 0) sm[w] = m;
    __syncthreads();
    m = fmaxf(fmaxf(sm[0], sm[1]), fmaxf(sm[2], sm[3]));

    float sum = 0.f;
#pragma unroll
    for (int s = 0; s < 9; ++s) sum += __expf(xs[s] - m);
#pragma unroll
    for (int off = 32; off >= 1; off >>= 1) sum += __shfl_xor(sum, off);
    if ((t & 63) == 0) ss[w] = sum;
    __syncthreads();
    sum = ss[0] + ss[1] + ss[2] + ss[3];
    const float inv = 1.f / sum;

#pragma unroll
    for (int s = 0; s < 9; ++s) {
        const int i = s * 256 + t;
        P[b * N + i] = __expf(xs[s] - m) * inv;
        Q[b * N + i] = target[b * N + i] + 1e-8f;
    }
    if (b == 0 && t == 0) out[0] = 0.f;
}

// --------------------------------------------------- first a-update -------
// 256 blocks x 256 thr, SAME bid->rows mapping as sk_pass: K = exp(-100C)
// written XCD-local; rowsums; A[b][i] = P[b][i]/rowsum_i for all 16 b.
__global__ __launch_bounds__(256) void sk_first(const float* __restrict__ C,
                                                float* __restrict__ K,
                                                const float* __restrict__ P,
                                                float* __restrict__ A) {
    __shared__ float rs[RPB];
    const int bid  = blockIdx.x;
    const int tid  = threadIdx.x;
    const int w    = tid >> 6;
    const int lane = tid & 63;
    const int i0   = bid * RPB;
    const int b0   = w * 4;

    for (int r = w; r < RPB; r += 4) {
        const int row = (i0 + r) * N;
        float s = 0.f;
#pragma unroll
        for (int it = 0; it < 9; ++it) {
            const int off = row + it * 256 + lane * 4;
            const float4 k4 = expk4(*(const float4*)(C + off));
            *(float4*)(K + off) = k4;
            s += (k4.x + k4.y) + (k4.z + k4.w);
        }
        s = wave_sum(s);
        if (lane == 0) rs[r] = s;
    }
    __syncthreads();

    if (lane < 16) {
#pragma unroll
        for (int k = 0; k < 3; ++k) {
            const int r = 4 * k + (lane >> 2);
            if (r < RPB) {
                const int idx = (b0 + (lane & 3)) * N + i0 + r;
                A[idx] = P[idx] / rs[r];
            }
        }
    }
}

// ----------------------------------------------------------- half-pass ----
// dst[b][i] = src[b][i] / sum_j K[i][j] * win[b][j]
// K staged in LDS (dedup across waves); win depth-2 register prefetch.
__global__ __launch_bounds__(256) void sk_pass(const float* __restrict__ K,
                                               const float* __restrict__ win,
                                               const float* __restrict__ src,
                                               float* __restrict__ dst) {
    __shared__ float4 Kl[KF4];   // 82944 B
    const int bid  = blockIdx.x;
    const int tid  = threadIdx.x;
    const int w    = tid >> 6;
    const int lane = tid & 63;
    const int i0   = bid * RPB;
    const int b0   = w * 4;

    // issue long-latency win prefetch (it=0,1) before staging so it overlaps
    float4 wb[3][4];
#pragma unroll
    for (int bb = 0; bb < 4; ++bb)
        wb[0][bb] = *(const float4*)(win + (b0 + bb) * N + lane * 4);
#pragma unroll
    for (int bb = 0; bb < 4; ++bb)
        wb[1][bb] = *(const float4*)(win + (b0 + bb) * N + 256 + lane * 4);

    // src slice (36 scalars per block; 3 per low lane)
    float sv[3] = {0.f, 0.f, 0.f};
    if (lane < 16) {
#pragma unroll
        for (int k = 0; k < 3; ++k) {
            const int r = 4 * k + (lane >> 2);
            if (r < RPB) sv[k] = src[(b0 + (lane & 3)) * N + i0 + r];
        }
    }

    stageK(Kl, K, i0);
    __syncthreads();

    float v[48];
#pragma unroll
    for (int k = 0; k < 48; ++k) v[k] = 0.f;

    float4 kb[2][RPB];
#pragma unroll
    for (int r = 0; r < RPB; ++r) kb[0][r] = Kl[r * F4R + lane];

#pragma unroll
    for (int it = 0; it < 9; ++it) {
        const int cur = it & 1, nxt = cur ^ 1;
        if (it < 8) {  // compile-time after unroll
            const int fi = (it + 1) * 64 + lane;
#pragma unroll
            for (int r = 0; r < RPB; ++r) kb[nxt][r] = Kl[r * F4R + fi];
        }
        if (it < 7) {  // win prefetch two iterations ahead
            const int j0 = (it + 2) * 256 + lane * 4;
#pragma unroll
            for (int bb = 0; bb < 4; ++bb)
                wb[(it + 2) % 3][bb] = *(const float4*)(win + (b0 + bb) * N + j0);
        }
#pragma unroll
        for (int r = 0; r < RPB; ++r) {
            const float4 k4 = kb[cur][r];
#pragma unroll
            for (int bb = 0; bb < 4; ++bb) {
                const float4 w4 = wb[it % 3][bb];
                float& a = v[r * 4 + bb];
                a = fmaf(k4.x, w4.x, a);
                a = fmaf(k4.y, w4.y, a);
                a = fmaf(k4.z, w4.z, a);
                a = fmaf(k4.w, w4.w, a);
            }
        }
    }

    fold48(v);

    if (lane < 16) {
#pragma unroll
        for (int k = 0; k < 3; ++k) {
            const int r = 4 * k + (lane >> 2);
            if (r < RPB) {
                const int idx = (b0 + (lane & 3)) * N + i0 + r;
                dst[idx] = sv[k] / v[k];
            }
        }
    }
}

// ------------------------------------------------------- fused b10+cost ---
// Per owned row j: s1_j = (K a10)_j, s2_j = (K.C a10)_j; contribution
// q_j/s1_j * s2_j summed over rows x batches; atomicAdd block partial /16.
__global__ __launch_bounds__(256) void sk_cost(const float* __restrict__ K,
                                               const float* __restrict__ C,
                                               const float* __restrict__ A,
                                               const float* __restrict__ Q,
                                               float* __restrict__ out) {
    __shared__ float4 Kl[KF4];
    __shared__ float wval[4];
    const int bid  = blockIdx.x;
    const int tid  = threadIdx.x;
    const int w    = tid >> 6;
    const int lane = tid & 63;
    const int i0   = bid * RPB;
    const int b0   = w * 4;

    stageK(Kl, K, i0);
    __syncthreads();

    float v1[48], v2[48];
#pragma unroll
    for (int k = 0; k < 48; ++k) { v1[k] = 0.f; v2[k] = 0.f; }

#pragma unroll
    for (int it = 0; it < 9; ++it) {
        const int j0 = it * 256 + lane * 4;
        float4 w4[4];
#pragma unroll
        for (int bb = 0; bb < 4; ++bb)
            w4[bb] = *(const float4*)(A + (b0 + bb) * N + j0);
#pragma unroll
        for (int r = 0; r < RPB; ++r) {
            const float4 k4 = Kl[r * F4R + it * 64 + lane];
            const float4 c4 = *(const float4*)(C + (i0 + r) * N + j0);
            float4 kc;
            kc.x = k4.x * c4.x;
            kc.y = k4.y * c4.y;
            kc.z = k4.z * c4.z;
            kc.w = k4.w * c4.w;
#pragma unroll
            for (int bb = 0; bb < 4; ++bb) {
                float& a1 = v1[r * 4 + bb];
                float& a2 = v2[r * 4 + bb];
                a1 = fmaf(k4.x, w4[bb].x, a1);
                a1 = fmaf(k4.y, w4[bb].y, a1);
                a1 = fmaf(k4.z, w4[bb].z, a1);
                a1 = fmaf(k4.w, w4[bb].w, a1);
                a2 = fmaf(kc.x, w4[bb].x, a2);
                a2 = fmaf(kc.y, w4[bb].y, a2);
                a2 = fmaf(kc.z, w4[bb].z, a2);
                a2 = fmaf(kc.w, w4[bb].w, a2);
            }
        }
    }

    fold48(v1);
    fold48(v2);

    // all 64 lanes: each 16-lane group duplicates -> scale 0.25
    float val = 0.f;
#pragma unroll
    for (int k = 0; k < 3; ++k) {
        const int r = 4 * k + ((lane & 15) >> 2);
        if (r < RPB) {
            const float qv = Q[(b0 + (lane & 3)) * N + i0 + r];
            val += qv / v1[k] * v2[k];
        }
    }
    val = wave_sum(val) * 0.25f;
    if (lane == 0) wval[w] = val;
    __syncthreads();
    if (tid == 0)
        atomicAdd(out, (wval[0] + wval[1] + wval[2] + wval[3]) * (1.f / 16.f));
}

}  // namespace

extern "C" void kernel_launch(void* const* d_in, const int* in_sizes, int n_in,
                              void* d_out, int out_size, void* d_ws, size_t ws_size,
                              hipStream_t stream) {
    const float* logits = (const float*)d_in[0];   // (B, 48, 48)
    const float* target = (const float*)d_in[1];   // (B, 48, 48)
    const float* C      = (const float*)d_in[2];   // (1, N, N)
    float* out = (float*)d_out;
    float* ws  = (float*)d_ws;

    float* A  = ws;                   // [B][N] a-hat
    float* Bh = A + NB;               // [B][N] b-hat
    float* P  = Bh + NB;              // [B][N]
    float* Q  = P + NB;               // [B][N]
    float* K  = Q + NB;               // [N][N]

    sk_init<<<B, 256, 0, stream>>>(logits, target, P, Q, out);
    sk_first<<<256, 256, 0, stream>>>(C, K, P, A);           // K + a1

    // b1..b9 and a2..a10 (18 passes); b10 fused into sk_cost
    for (int t = 1; t <= 9; ++t) {
        sk_pass<<<256, 256, 0, stream>>>(K, A, Q, Bh);       // b_t
        sk_pass<<<256, 256, 0, stream>>>(K, Bh, P, A);       // a_{t+1}
    }

    sk_cost<<<256, 256, 0, stream>>>(K, C, A, Q, out);
}